// Round 7
// baseline (96.675 us; speedup 1.0000x reference)
//
#include <hip/hip_runtime.h>
#include <cstdint>

typedef __bf16 bf16x8 __attribute__((ext_vector_type(8)));
typedef float floatx4 __attribute__((ext_vector_type(4)));

// M = 4096 rows, C(K) = 256. ROUND 7 = INSTRUMENTATION ROUND.
// R6 pipeline kept byte-identical (total = 48.6 + gemm + combine identity
// calibrated over R1/R3/R6). Appended: probe_loads -- an exact replica of
// gemm_wave's grid/mapping/fragment loads with MFMA replaced by XOR sink.
// Its duration = (this round's total) - 91.4 - 1 gap. This isolates the
// load path, the last uninstrumented phase of the structure-invariant
// ~40 us GEMM mystery (six variants, all 40-45 us vs <=8 us budget).
//
// Staged layout: Xs[rb(32)][s(4)][kk(2)][rowhi(8)][quad(4)][rowlo(16)][8 bf16]
// holding X[row = rb*128+rowhi*16+rowlo][k = s*64+kk*32+quad*8+j].

#define OFF_X     (0u)
#define OFF_Y     (2u*1024*1024)
#define OFF_PMAX  (4u*1024*1024)
#define OFF_PSUM  (5u*1024*1024)
#define OFF_DIAG  (6u*1024*1024)
#define OFF_LPART (OFF_DIAG + 16384u)
#define OFF_CPART (OFF_LPART + 256u)
#define OFF_CNT   (OFF_CPART + 256u)   // cnt[0]: combine arrival counter
#define OFF_SCR   (8u*1024*1024)       // probe sink (never read)

// ---------------------------------------------------------------------------
// K0: fp32 -> staged bf16. One block per (b,n) slab. Block 0 zeroes cnt.
// ---------------------------------------------------------------------------
__global__ __launch_bounds__(256) void transpose_stage(
    const float* __restrict__ pred, const float* __restrict__ gt,
    unsigned short* __restrict__ Xs, unsigned short* __restrict__ Ys,
    int* __restrict__ cnt) {
  int blk = blockIdx.x;
  const int t = threadIdx.x;
  if (blk == 0 && t < 33) cnt[t] = 0;
  const float* src;
  unsigned short* dst;
  int slab;
  if (blk < 256) { src = pred; dst = Xs; slab = blk; }
  else           { src = gt;   dst = Ys; slab = blk - 256; }
  const float* sb = src + slab * 4096;
  const int rb = slab >> 3, rowhi = slab & 7;
  #pragma unroll
  for (int half = 0; half < 2; ++half) {
    int c_ = half * 256 + t;                 // chunk id within slab, 0..511
    int rowlo = c_ & 15;
    int quad  = (c_ >> 4) & 3;
    int kk    = (c_ >> 6) & 1;
    int s     = c_ >> 7;
    int k0 = s * 64 + kk * 32 + quad * 8;
    unsigned int packed[4];
    #pragma unroll
    for (int jj = 0; jj < 4; ++jj) {
      unsigned int lohi[2];
      #pragma unroll
      for (int e = 0; e < 2; ++e) {
        float f = sb[(k0 + jj * 2 + e) * 16 + rowlo];
        unsigned int u = __float_as_uint(f);
        lohi[e] = (u + 0x7FFFu + ((u >> 16) & 1u)) >> 16;   // RNE -> bf16
      }
      packed[jj] = lohi[0] | (lohi[1] << 16);
    }
    unsigned short* o = dst + rb * 32768 +
        (unsigned)(s * 1024 + kk * 512 + rowhi * 64 + quad * 16 + rowlo) * 8;
    uint4 v; v.x = packed[0]; v.y = packed[1]; v.z = packed[2]; v.w = packed[3];
    *reinterpret_cast<uint4*>(o) = v;
  }
}

// ---------------------------------------------------------------------------
// K1: per-wave 64x64 GEMM tile, no LDS, no barriers (R6, unchanged).
// ---------------------------------------------------------------------------
__global__ __launch_bounds__(256, 4) void gemm_wave(
    const unsigned short* __restrict__ Xs, const unsigned short* __restrict__ Ys,
    float* __restrict__ pmax, float* __restrict__ psum, float* __restrict__ diag) {
  const int t = threadIdx.x;
  const int wv = t >> 6, lane = t & 63;
  const int b = blockIdx.x;
  const int xcd = b & 7, slot = b >> 3;            // slot 0..127
  const int rowb = ((xcd >> 1) << 4) | (slot & 15); // 0..63 (64-row tiles)
  const int colb = ((xcd & 1) << 3) | (slot >> 4);  // 0..15 (256-col groups)
  const int hh = rowb & 1, ch = wv & 1;
  const unsigned short* Ab = Xs + (rowb >> 1) * 32768 + (unsigned)lane * 8;
  const unsigned short* Bb = Ys + ((colb << 1) | (wv >> 1)) * 32768 +
                             (unsigned)lane * 8;

  floatx4 acc[4][4];
  const floatx4 zero = {0.f, 0.f, 0.f, 0.f};
  #pragma unroll
  for (int i = 0; i < 4; ++i)
    #pragma unroll
    for (int j = 0; j < 4; ++j) acc[i][j] = zero;

  #pragma unroll
  for (int ks = 0; ks < 8; ++ks) {                 // K-step of 32
    const unsigned off = (unsigned)(((ks >> 1) * 1024 + (ks & 1) * 512)) * 8;
    bf16x8 a[4], bf[4];
    #pragma unroll
    for (int fr = 0; fr < 4; ++fr)
      a[fr] = *reinterpret_cast<const bf16x8*>(
          Ab + off + (unsigned)((hh * 4 + fr) * 64) * 8);
    #pragma unroll
    for (int fc = 0; fc < 4; ++fc)
      bf[fc] = *reinterpret_cast<const bf16x8*>(
          Bb + off + (unsigned)((ch * 4 + fc) * 64) * 8);
    #pragma unroll
    for (int fr = 0; fr < 4; ++fr)
      #pragma unroll
      for (int fc = 0; fc < 4; ++fc)
        acc[fr][fc] = __builtin_amdgcn_mfma_f32_16x16x32_bf16(
            a[fr], bf[fc], acc[fr][fc], 0, 0, 0);
  }

  const int quad = lane >> 4, lc = lane & 15;

  if (colb * 4 + wv == rowb) {
    #pragma unroll
    for (int fr = 0; fr < 4; ++fr)
      #pragma unroll
      for (int r = 0; r < 4; ++r)
        if (lc == quad * 4 + r)
          diag[rowb * 64 + fr * 16 + lc] = acc[fr][fr][r];
  }

  #pragma unroll
  for (int fr = 0; fr < 4; ++fr) {
    #pragma unroll
    for (int r = 0; r < 4; ++r) {
      float v0 = acc[fr][0][r], v1 = acc[fr][1][r];
      float v2 = acc[fr][2][r], v3 = acc[fr][3][r];
      float m = fmaxf(fmaxf(v0, v1), fmaxf(v2, v3));
      #pragma unroll
      for (int sh = 1; sh < 16; sh <<= 1) m = fmaxf(m, __shfl_xor(m, sh, 64));
      float ss = __expf(v0 - m) + __expf(v1 - m) +
                 __expf(v2 - m) + __expf(v3 - m);
      #pragma unroll
      for (int sh = 1; sh < 16; sh <<= 1) ss += __shfl_xor(ss, sh, 64);
      if (lc == 0) {
        int grow = rowb * 64 + fr * 16 + quad * 4 + r;
        int p = grow * 64 + colb * 4 + wv;
        pmax[p] = m; psum[p] = ss;
      }
    }
  }
}

// ---------------------------------------------------------------------------
// K2: per-row combine + fused finalize (R6, unchanged).
// ---------------------------------------------------------------------------
__global__ __launch_bounds__(256) void combine_rows(
    const float* __restrict__ pmax, const float* __restrict__ psum,
    const float* __restrict__ diag,
    float* __restrict__ lpart, float* __restrict__ cpart,
    int* __restrict__ cnt, float* __restrict__ out) {
  int row = blockIdx.x * 256 + threadIdx.x;
  const float* pm = pmax + row * 64;
  const float* ps = psum + row * 64;
  float M = -3.4e38f;
  #pragma unroll 8
  for (int b = 0; b < 64; ++b) M = fmaxf(M, pm[b]);
  float S = 0.f;
  #pragma unroll 8
  for (int b = 0; b < 64; ++b) S += ps[b] * __expf(pm[b] - M);
  float d = diag[row];
  float lossr = logf(S) + M - d;
  float corr = (d == M) ? 1.f : 0.f;
  #pragma unroll
  for (int sh = 1; sh < 64; sh <<= 1) {
    lossr += __shfl_xor(lossr, sh, 64);
    corr  += __shfl_xor(corr,  sh, 64);
  }
  __shared__ float ls[4], cs[4];
  int wave = threadIdx.x >> 6, lane = threadIdx.x & 63;
  if (lane == 0) { ls[wave] = lossr; cs[wave] = corr; }
  __syncthreads();
  if (threadIdx.x == 0) {
    lpart[blockIdx.x] = ls[0] + ls[1] + ls[2] + ls[3];
    cpart[blockIdx.x] = cs[0] + cs[1] + cs[2] + cs[3];
    __threadfence();                     // release per-block partial
    if (atomicAdd(cnt, 1) == 15) {       // last arriver finalizes
      __threadfence();                   // acquire all partials
      float L = 0.f, C = 0.f;
      for (int i = 0; i < 16; ++i) { L += lpart[i]; C += cpart[i]; }
      out[0] = L * (1.f / 4096.f);
      out[1] = C * (100.f / 4096.f);
    }
  }
}

// ---------------------------------------------------------------------------
// PROBE: exact replica of gemm_wave's grid / block mapping / all 64 fragment
// loads per lane, MFMA replaced by XOR accumulation (serial dep on data only;
// loads can issue in bulk). Sink stored to dead scratch so nothing is DCE'd.
// Runs AFTER the real pipeline -> same cache state gemm_wave saw, output
// already written. Duration read from total-time decomposition (or top-5 if
// it exceeds the ~42 us fills).
// ---------------------------------------------------------------------------
__global__ __launch_bounds__(256, 4) void probe_loads(
    const unsigned short* __restrict__ Xs, const unsigned short* __restrict__ Ys,
    uint4* __restrict__ scratch) {
  const int t = threadIdx.x;
  const int wv = t >> 6, lane = t & 63;
  const int b = blockIdx.x;
  const int xcd = b & 7, slot = b >> 3;
  const int rowb = ((xcd >> 1) << 4) | (slot & 15);
  const int colb = ((xcd & 1) << 3) | (slot >> 4);
  const int hh = rowb & 1, ch = wv & 1;
  const unsigned short* Ab = Xs + (rowb >> 1) * 32768 + (unsigned)lane * 8;
  const unsigned short* Bb = Ys + ((colb << 1) | (wv >> 1)) * 32768 +
                             (unsigned)lane * 8;
  uint4 sink = {0u, 0u, 0u, 0u};
  #pragma unroll
  for (int ks = 0; ks < 8; ++ks) {
    const unsigned off = (unsigned)(((ks >> 1) * 1024 + (ks & 1) * 512)) * 8;
    #pragma unroll
    for (int fr = 0; fr < 4; ++fr) {
      uint4 v = *reinterpret_cast<const uint4*>(
          Ab + off + (unsigned)((hh * 4 + fr) * 64) * 8);
      sink.x ^= v.x; sink.y ^= v.y; sink.z ^= v.z; sink.w ^= v.w;
    }
    #pragma unroll
    for (int fc = 0; fc < 4; ++fc) {
      uint4 v = *reinterpret_cast<const uint4*>(
          Bb + off + (unsigned)((ch * 4 + fc) * 64) * 8);
      sink.x ^= v.x; sink.y ^= v.y; sink.z ^= v.z; sink.w ^= v.w;
    }
  }
  if (lane == 0) scratch[b * 4 + wv] = sink;   // dead store, prevents DCE
}

extern "C" void kernel_launch(void* const* d_in, const int* in_sizes, int n_in,
                              void* d_out, int out_size, void* d_ws, size_t ws_size,
                              hipStream_t stream) {
  const float* pred = (const float*)d_in[0];
  const float* gt   = (const float*)d_in[1];
  char* w = (char*)d_ws;
  unsigned short* Xbf = (unsigned short*)(w + OFF_X);
  unsigned short* Ybf = (unsigned short*)(w + OFF_Y);
  float* pmax  = (float*)(w + OFF_PMAX);
  float* psum  = (float*)(w + OFF_PSUM);
  float* diag  = (float*)(w + OFF_DIAG);
  float* lpart = (float*)(w + OFF_LPART);
  float* cpart = (float*)(w + OFF_CPART);
  int*   cnt   = (int*)(w + OFF_CNT);
  uint4* scr   = (uint4*)(w + OFF_SCR);
  float* out   = (float*)d_out;

  transpose_stage<<<512, 256, 0, stream>>>(pred, gt, Xbf, Ybf, cnt);
  gemm_wave<<<1024, 256, 0, stream>>>(Xbf, Ybf, pmax, psum, diag);
  combine_rows<<<16, 256, 0, stream>>>(pmax, psum, diag, lpart, cpart, cnt, out);
  probe_loads<<<1024, 256, 0, stream>>>(Xbf, Ybf, scr);   // diagnostic only
}